// Round 7
// baseline (48.224 us; speedup 1.0000x reference)
//
#include <hip/hip_runtime.h>
#include <hip/hip_fp16.h>

#define N_NODES 100000
#define N_EDGES 1600000
#define GRID_N  2048
#define NBI     6250          // node block-tiles of 16 nodes

typedef float  f32x4 __attribute__((ext_vector_type(4)));
typedef int    i32x4 __attribute__((ext_vector_type(4)));
typedef long long i64x2 __attribute__((ext_vector_type(2)));

// ---------- kernel 1: per-node scalars -> packed half2 {s_src, s_dst} ----------
__global__ __launch_bounds__(256) void node_kernel(
        const float* __restrict__ h1, const float* __restrict__ h2,
        const float* __restrict__ W1, const float* __restrict__ W2,
        __half2* __restrict__ pair) {
    __shared__ float wf[256];
    const int t = threadIdx.x;
    {
        float acc = 0.f;
#pragma unroll
        for (int k = 0; k < 16; ++k) acc += W1[t * 16 + k] * W2[k];
        wf[t] = acc;
    }
    __syncthreads();

    const int li = t & 15;
    const int g  = t >> 4;

    const f32x4* wf4 = (const f32x4*)wf;
    const f32x4 ws1 = wf4[li];        // w[0:64)    pairs h1 (src half)
    const f32x4 ws2 = wf4[16 + li];   // w[64:128)  pairs h2 (src half)
    const f32x4 wd1 = wf4[32 + li];   // w[128:192) pairs h1 (dst half)
    const f32x4 wd2 = wf4[48 + li];   // w[192:256) pairs h2 (dst half)

    for (int bi = blockIdx.x; bi < NBI; bi += GRID_N) {
        const int node = bi * 16 + g;

        const f32x4 a = __builtin_nontemporal_load(
            (const f32x4*)(h1 + (size_t)node * 64) + li);
        const f32x4 b = __builtin_nontemporal_load(
            (const f32x4*)(h2 + (size_t)node * 64) + li);

        float ps = a.x * ws1.x + a.y * ws1.y + a.z * ws1.z + a.w * ws1.w
                 + b.x * ws2.x + b.y * ws2.y + b.z * ws2.z + b.w * ws2.w;
        float pd = a.x * wd1.x + a.y * wd1.y + a.z * wd1.z + a.w * wd1.w
                 + b.x * wd2.x + b.y * wd2.y + b.z * wd2.z + b.w * wd2.w;

#pragma unroll
        for (int off = 1; off < 16; off <<= 1) {
            ps += __shfl_xor(ps, off);
            pd += __shfl_xor(pd, off);
        }
        if (li == 0) pair[node] = __floats2half2_rn(ps, pd);
    }
}

// ---------- kernel 2: edge gather + add, 4 edges/thread ----------
__global__ __launch_bounds__(256) void edge_kernel(
        const void* __restrict__ edges,
        const __half2* __restrict__ pair,
        const float* __restrict__ b1, const float* __restrict__ W2,
        const float* __restrict__ b2,
        float* __restrict__ out) {
    const int t   = threadIdx.x;
    const int tid = blockIdx.x * 256 + t;      // 1563 blocks; 400000 active threads

    float c = b2[0];
#pragma unroll
    for (int k = 0; k < 16; ++k) c += b1[k] * W2[k];

    // int64 edges (LE, values in [0,1e5)) have all odd 32-bit words == 0;
    // int32 edges have random indices there -> ballot over 64 samples decides.
    const int* e32 = (const int*)edges;
    const bool is64 = (__ballot(e32[2 * (t & 63) + 1] != 0) == 0ULL);

    if (tid >= N_EDGES / 4) return;            // 400000 * 4 = 1.6M exact

    int s[4], d[4];
    if (is64) {
        const i64x2* es = (const i64x2*)edges;                  // src row
        const i64x2* ed = es + (N_EDGES / 2);                   // dst row
        i64x2 s01 = __builtin_nontemporal_load(es + 2 * tid);
        i64x2 s23 = __builtin_nontemporal_load(es + 2 * tid + 1);
        i64x2 d01 = __builtin_nontemporal_load(ed + 2 * tid);
        i64x2 d23 = __builtin_nontemporal_load(ed + 2 * tid + 1);
        s[0] = (int)s01.x; s[1] = (int)s01.y; s[2] = (int)s23.x; s[3] = (int)s23.y;
        d[0] = (int)d01.x; d[1] = (int)d01.y; d[2] = (int)d23.x; d[3] = (int)d23.y;
    } else {
        const i32x4* es = (const i32x4*)edges;
        const i32x4* ed = (const i32x4*)((const int*)edges + N_EDGES);
        i32x4 sv = __builtin_nontemporal_load(es + tid);
        i32x4 dv = __builtin_nontemporal_load(ed + tid);
        s[0] = sv.x; s[1] = sv.y; s[2] = sv.z; s[3] = sv.w;
        d[0] = dv.x; d[1] = dv.y; d[2] = dv.z; d[3] = dv.w;
    }

    __half2 ph[4], qh[4];
#pragma unroll
    for (int i = 0; i < 4; ++i) { ph[i] = pair[s[i]]; qh[i] = pair[d[i]]; }

    f32x4 r;
    r.x = __low2float(ph[0]) + __high2float(qh[0]) + c;
    r.y = __low2float(ph[1]) + __high2float(qh[1]) + c;
    r.z = __low2float(ph[2]) + __high2float(qh[2]) + c;
    r.w = __low2float(ph[3]) + __high2float(qh[3]) + c;
    __builtin_nontemporal_store(r, (f32x4*)out + tid);
}

extern "C" void kernel_launch(void* const* d_in, const int* in_sizes, int n_in,
                              void* d_out, int out_size, void* d_ws, size_t ws_size,
                              hipStream_t stream) {
    const float* h1 = (const float*)d_in[0];
    const float* h2 = (const float*)d_in[1];
    const float* W1 = (const float*)d_in[2];
    const float* b1 = (const float*)d_in[3];
    const float* W2 = (const float*)d_in[4];
    const float* b2 = (const float*)d_in[5];
    const void*  edges = d_in[6];

    __half2* pair = (__half2*)d_ws;
    float*   out  = (float*)d_out;

    // MEASUREMENT ROUND: node_kernel launched 3x (idempotent — identical writes).
    // dur_us ≈ dur_R6 + 2*(t_node + t_dispatch); splits node vs edge cost.
    node_kernel<<<GRID_N, 256, 0, stream>>>(h1, h2, W1, W2, pair);
    node_kernel<<<GRID_N, 256, 0, stream>>>(h1, h2, W1, W2, pair);
    node_kernel<<<GRID_N, 256, 0, stream>>>(h1, h2, W1, W2, pair);
    edge_kernel<<<(N_EDGES / 4 + 255) / 256, 256, 0, stream>>>(edges, pair, b1, W2, b2, out);
}

// Round 8
// 31.825 us; speedup vs baseline: 1.5153x; 1.5153x over previous
//
#include <hip/hip_runtime.h>
#include <hip/hip_fp16.h>

#define N_NODES 100000
#define N_EDGES 1600000
#define GRID_N  2048
#define NBI     6250          // node block-tiles of 16 nodes

typedef float  f32x4 __attribute__((ext_vector_type(4)));
typedef int    i32x4 __attribute__((ext_vector_type(4)));
typedef long long i64x2 __attribute__((ext_vector_type(2)));

// ---------- kernel 1: per-node scalars -> packed half2 {s_src, s_dst} ----------
__global__ __launch_bounds__(256) void node_kernel(
        const float* __restrict__ h1, const float* __restrict__ h2,
        const float* __restrict__ W1, const float* __restrict__ W2,
        __half2* __restrict__ pair) {
    __shared__ float wf[256];
    const int t = threadIdx.x;
    {
        float acc = 0.f;
#pragma unroll
        for (int k = 0; k < 16; ++k) acc += W1[t * 16 + k] * W2[k];
        wf[t] = acc;
    }
    __syncthreads();

    const int li = t & 15;
    const int g  = t >> 4;

    const f32x4* wf4 = (const f32x4*)wf;
    const f32x4 ws1 = wf4[li];        // w[0:64)    pairs h1 (src half)
    const f32x4 ws2 = wf4[16 + li];   // w[64:128)  pairs h2 (src half)
    const f32x4 wd1 = wf4[32 + li];   // w[128:192) pairs h1 (dst half)
    const f32x4 wd2 = wf4[48 + li];   // w[192:256) pairs h2 (dst half)

    for (int bi = blockIdx.x; bi < NBI; bi += GRID_N) {
        const int node = bi * 16 + g;

        const f32x4 a = ((const f32x4*)(h1 + (size_t)node * 64))[li];
        const f32x4 b = ((const f32x4*)(h2 + (size_t)node * 64))[li];

        float ps = a.x * ws1.x + a.y * ws1.y + a.z * ws1.z + a.w * ws1.w
                 + b.x * ws2.x + b.y * ws2.y + b.z * ws2.z + b.w * ws2.w;
        float pd = a.x * wd1.x + a.y * wd1.y + a.z * wd1.z + a.w * wd1.w
                 + b.x * wd2.x + b.y * wd2.y + b.z * wd2.z + b.w * wd2.w;

#pragma unroll
        for (int off = 1; off < 16; off <<= 1) {
            ps += __shfl_xor(ps, off);
            pd += __shfl_xor(pd, off);
        }
        if (li == 0) pair[node] = __floats2half2_rn(ps, pd);
    }
}

// ---------- kernel 2: edge gather + add, 4 edges/thread ----------
__global__ __launch_bounds__(256) void edge_kernel(
        const void* __restrict__ edges,
        const __half2* __restrict__ pair,
        const float* __restrict__ b1, const float* __restrict__ W2,
        const float* __restrict__ b2,
        float* __restrict__ out) {
    const int t   = threadIdx.x;
    const int tid = blockIdx.x * 256 + t;      // 1563 blocks; 400000 active threads

    float c = b2[0];
#pragma unroll
    for (int k = 0; k < 16; ++k) c += b1[k] * W2[k];

    // int64 edges (LE, values in [0,1e5)) have all odd 32-bit words == 0;
    // int32 edges have random indices there -> ballot over 64 samples decides.
    const int* e32 = (const int*)edges;
    const bool is64 = (__ballot(e32[2 * (t & 63) + 1] != 0) == 0ULL);

    if (tid >= N_EDGES / 4) return;            // 400000 * 4 = 1.6M exact

    int s[4], d[4];
    if (is64) {
        const i64x2* es = (const i64x2*)edges;                  // src row
        const i64x2* ed = es + (N_EDGES / 2);                   // dst row
        i64x2 s01 = es[2 * tid];
        i64x2 s23 = es[2 * tid + 1];
        i64x2 d01 = ed[2 * tid];
        i64x2 d23 = ed[2 * tid + 1];
        s[0] = (int)s01.x; s[1] = (int)s01.y; s[2] = (int)s23.x; s[3] = (int)s23.y;
        d[0] = (int)d01.x; d[1] = (int)d01.y; d[2] = (int)d23.x; d[3] = (int)d23.y;
    } else {
        const i32x4* es = (const i32x4*)edges;
        const i32x4* ed = (const i32x4*)((const int*)edges + N_EDGES);
        i32x4 sv = es[tid];
        i32x4 dv = ed[tid];
        s[0] = sv.x; s[1] = sv.y; s[2] = sv.z; s[3] = sv.w;
        d[0] = dv.x; d[1] = dv.y; d[2] = dv.z; d[3] = dv.w;
    }

    __half2 ph[4], qh[4];
#pragma unroll
    for (int i = 0; i < 4; ++i) { ph[i] = pair[s[i]]; qh[i] = pair[d[i]]; }

    f32x4 r;
    r.x = __low2float(ph[0]) + __high2float(qh[0]) + c;
    r.y = __low2float(ph[1]) + __high2float(qh[1]) + c;
    r.z = __low2float(ph[2]) + __high2float(qh[2]) + c;
    r.w = __low2float(ph[3]) + __high2float(qh[3]) + c;
    ((f32x4*)out)[tid] = r;
}

extern "C" void kernel_launch(void* const* d_in, const int* in_sizes, int n_in,
                              void* d_out, int out_size, void* d_ws, size_t ws_size,
                              hipStream_t stream) {
    const float* h1 = (const float*)d_in[0];
    const float* h2 = (const float*)d_in[1];
    const float* W1 = (const float*)d_in[2];
    const float* b1 = (const float*)d_in[3];
    const float* W2 = (const float*)d_in[4];
    const float* b2 = (const float*)d_in[5];
    const void*  edges = d_in[6];

    __half2* pair = (__half2*)d_ws;
    float*   out  = (float*)d_out;

    node_kernel<<<GRID_N, 256, 0, stream>>>(h1, h2, W1, W2, pair);
    edge_kernel<<<(N_EDGES / 4 + 255) / 256, 256, 0, stream>>>(edges, pair, b1, W2, b2, out);
}